// Round 14
// baseline (624.090 us; speedup 1.0000x reference)
//
#include <hip/hip_runtime.h>

#define T_STEPS 365
#define BATCH   2048
#define INP     9
#define HID     50
#define MB      16          // batch per block (MFMA col dim)
#define NBLK    (BATCH/MB)  // 128
#define NT      192         // 3 waves: A = layer0 state-wave, B1/B2 = layer1+FC
#define L2E     1.4426950408889634f

typedef __attribute__((ext_vector_type(8))) short short8;
typedef __attribute__((ext_vector_type(4))) float float4v;

#define MFMA_(A, B, C) __builtin_amdgcn_mfma_f32_16x16x32_bf16((A), (B), (C), 0, 0, 0)

__device__ __forceinline__ unsigned f2bf(float v) {
    unsigned u = __builtin_bit_cast(unsigned, v);
    return (u + 0x7FFFu + ((u >> 16) & 1u)) >> 16;
}

// rcp-merged LSTM cell: 5 exp2 + 3 rcp. Inputs exp2-prescaled
// (-L2E for i,f,o; -2L2E for g).
__device__ __forceinline__ float cell_(float a0, float a1, float a2, float a3,
                                       float& c) {
    const float Ei = __builtin_amdgcn_exp2f(a0);
    const float Ef = __builtin_amdgcn_exp2f(a1);
    const float Eg = __builtin_amdgcn_exp2f(a2);
    const float Eo = __builtin_amdgcn_exp2f(a3);
    const float ig = (1.f - Eg) * __builtin_amdgcn_rcpf((1.f + Ei) * (1.f + Eg));
    c = __builtin_amdgcn_rcpf(1.f + Ef) * c + ig;
    const float Ec = __builtin_amdgcn_exp2f(c * (-2.f * L2E));
    return (1.f - Ec) * __builtin_amdgcn_rcpf((1.f + Eo) * (1.f + Ec));
}

// CU-local monotonic flag ops (LDS; single writer per counter).
__device__ __forceinline__ void spin_ge(volatile unsigned* f, unsigned tgt) {
    while (*f < tgt) __builtin_amdgcn_s_sleep(2);
    asm volatile("" ::: "memory");
    __builtin_amdgcn_sched_barrier(0);
}
__device__ __forceinline__ void post_(volatile unsigned* f, unsigned val, bool lead) {
    asm volatile("s_waitcnt lgkmcnt(0)" ::: "memory");   // data writes retired first
    if (lead) *f = val;
    __builtin_amdgcn_sched_barrier(0);
}

// Slot layout (ushort units): off = (k>>3)*128 + m*8 + (k&7).
// SLOT[s]: k 0-49 = h0, 50-58 = x, 59-63 = zero.  H1B[p]: k 0-49 = h1.
// A wave's b128 fragment read is a contiguous 1 KB block -> conflict-free.

// Producer/consumer LSTM, 3 waves, NO barrier in the main loop:
//   wave A  : full layer0 recurrence; its step-t fragment reads are its own
//             step-(t-1) writes (program order, zero sync). Publishes h0(t)+x(t+1)
//             into a 4-deep slot ring; only syncs if a consumer lags > 3 steps.
//   wave B1 : layer1 tiles 0-6   (one step behind, fed by the ring)
//   wave B2 : layer1 tiles 7-12 + FC spare row 200 + out stores
// Flags: FL[0]=PROD (A steps done), FL[8]=FB1, FL[16]=FB2 (B steps done).
__global__ __launch_bounds__(NT, 1)
void lstm_pc(const float* __restrict__ x,
             const float* __restrict__ w_ih0, const float* __restrict__ w_hh0,
             const float* __restrict__ b_ih0, const float* __restrict__ b_hh0,
             const float* __restrict__ w_ih1, const float* __restrict__ w_hh1,
             const float* __restrict__ b_ih1, const float* __restrict__ b_hh1,
             const float* __restrict__ fc_w, const float* __restrict__ fc_b,
             float* __restrict__ out)
{
    __shared__ __align__(16) unsigned short SLOT[4][1024];  // 8 KB ring
    __shared__ __align__(16) unsigned short H1B[2][1024];   // 4 KB h1 parity
    __shared__ unsigned FL[24];

    const int tid = threadIdx.x;
    const int w   = tid >> 6;
    const int lid = tid & 63;
    const int m   = lid & 15;
    const int g   = lid >> 4;
    const int kb8 = g * 8;
    const int b0  = blockIdx.x * MB;
    const bool lead = (lid == 0);

    // ---- LDS init ----
    for (int i = tid; i < 4 * 1024 + 2 * 1024; i += NT)
        (&SLOT[0][0])[i] = 0;
    if (tid < 24) FL[tid] = 0;
    __syncthreads();

    if (w == 0) {
        // ================= wave A: layer0 state-wave =================
        short8 wk[13][2];
        float  bs[13][4], cs[13], hv[13];
        #pragma unroll
        for (int T = 0; T < 13; ++T) {
            const int r = T * 16 + m;
            const bool rv = (r < 4 * HID);
            const int orig = (r & 3) * HID + (r >> 2);
            const float rsc = ((r & 3) == 2) ? (-2.f * L2E) : (-L2E);
            #pragma unroll
            for (int q = 0; q < 2; ++q) {
                short8 a{};
                #pragma unroll
                for (int j = 0; j < 8; ++j) {
                    const int k = q * 32 + kb8 + j;
                    float v = 0.f;
                    if (rv) {
                        if (k < HID)            v = w_hh0[orig * HID + k] * rsc;
                        else if (k < HID + INP) v = w_ih0[orig * INP + (k - HID)] * rsc;
                    }
                    a[j] = (short)f2bf(v);
                }
                wk[T][q] = a;
            }
            #pragma unroll
            for (int rr = 0; rr < 4; ++rr) {
                const int row = T * 16 + g * 4 + rr;
                const float bsc = (rr == 2) ? (-2.f * L2E) : (-L2E);
                bs[T][rr] = (row < 4 * HID)
                    ? (b_ih0[rr * HID + (row >> 2)] + b_hh0[rr * HID + (row >> 2)]) * bsc
                    : 0.f;
            }
            cs[T] = 0.f;
        }

        // x staging: x(0) -> SLOT[3]; xc = x(1), xn = x(2)
        float xc[3] = {0.f, 0.f, 0.f}, xn[3] = {0.f, 0.f, 0.f};
        #pragma unroll
        for (int q = 0; q < 3; ++q) {
            const int xi = lid * 3 + q;
            if (xi < MB * INP) {
                const int mx = xi / INP, j = xi - mx * INP;
                SLOT[3][((HID + j) >> 3) * 128 + mx * 8 + ((HID + j) & 7)] =
                    (unsigned short)f2bf(x[(size_t)(b0 + mx) * INP + j]);
                xc[q] = x[((size_t)1 * BATCH + b0 + mx) * INP + j];
                xn[q] = x[((size_t)2 * BATCH + b0 + mx) * INP + j];
            }
        }

        for (int t = 0; t < T_STEPS; ++t) {
            // early-issue consumer-progress reads (latency hides under compute)
            const unsigned c1 = ((volatile unsigned*)FL)[8];
            const unsigned c2 = ((volatile unsigned*)FL)[16];

            // fragments = A's OWN step-(t-1) writes: program order, no sync
            const unsigned short* sp = &SLOT[(t + 3) & 3][0];
            const short8 f0 = *(const short8*)&sp[g * 128 + m * 8];
            const short8 f1 = *(const short8*)&sp[(4 + g) * 128 + m * 8];

            #pragma unroll
            for (int T = 0; T < 13; ++T) {
                float4v acc = {bs[T][0], bs[T][1], bs[T][2], bs[T][3]};
                acc = MFMA_(wk[T][0], f0, acc);
                acc = MFMA_(wk[T][1], f1, acc);
                hv[T] = cell_(acc[0], acc[1], acc[2], acc[3], cs[T]);
            }

            // overwrite guard: slot t&3 holds h0(t-4), read by B at step t-4
            if (t >= 4 && (c1 < (unsigned)(t - 3) || c2 < (unsigned)(t - 3))) {
                spin_ge(&FL[8],  (unsigned)(t - 3));
                spin_ge(&FL[16], (unsigned)(t - 3));
            }
            asm volatile("" ::: "memory");
            __builtin_amdgcn_sched_barrier(0);

            unsigned short* dp = &SLOT[t & 3][0];
            #pragma unroll
            for (int T = 0; T < 12; ++T) {        // u = 4T+g <= 47, always valid
                const int u = T * 4 + g;
                dp[(u >> 3) * 128 + m * 8 + (u & 7)] = (unsigned short)f2bf(hv[T]);
            }
            if (g < 2) {                           // tile 12: units 48,49
                const int u = 48 + g;
                dp[(u >> 3) * 128 + m * 8 + (u & 7)] = (unsigned short)f2bf(hv[12]);
            }
            #pragma unroll
            for (int q = 0; q < 3; ++q) {          // x(t+1) into this slot
                const int xi = lid * 3 + q;
                if (xi < MB * INP) {
                    const int mx = xi / INP, j = xi - mx * INP;
                    dp[((HID + j) >> 3) * 128 + mx * 8 + ((HID + j) & 7)] =
                        (unsigned short)f2bf(xc[q]);
                }
            }
            post_(&FL[0], (unsigned)(t + 1), lead);

            #pragma unroll
            for (int q = 0; q < 3; ++q) xc[q] = xn[q];
            if (t + 3 < T_STEPS) {
                #pragma unroll
                for (int q = 0; q < 3; ++q) {
                    const int xi = lid * 3 + q;
                    if (xi < MB * INP) {
                        const int mx = xi / INP, j = xi - mx * INP;
                        xn[q] = x[((size_t)(t + 3) * BATCH + b0 + mx) * INP + j];
                    }
                }
            }
        }
    } else if (w == 1) {
        // ================= wave B1: layer1 tiles 0..6 =================
        short8 wk1[7][2], wk2[7][2];
        float  bs[7][4], cs[7];
        #pragma unroll
        for (int i = 0; i < 7; ++i) {
            const int T = i;
            const int r = T * 16 + m;
            const bool rv = (r < 4 * HID);
            const int orig = (r & 3) * HID + (r >> 2);
            const float rsc = ((r & 3) == 2) ? (-2.f * L2E) : (-L2E);
            #pragma unroll
            for (int q = 0; q < 2; ++q) {
                short8 a{}, b{};
                #pragma unroll
                for (int j = 0; j < 8; ++j) {
                    const int k = q * 32 + kb8 + j;
                    float v1 = 0.f, v2 = 0.f;
                    if (rv && k < HID) {
                        v1 = w_ih1[orig * HID + k] * rsc;
                        v2 = w_hh1[orig * HID + k] * rsc;
                    }
                    a[j] = (short)f2bf(v1);
                    b[j] = (short)f2bf(v2);
                }
                wk1[i][q] = a; wk2[i][q] = b;
            }
            #pragma unroll
            for (int rr = 0; rr < 4; ++rr) {
                const int row = T * 16 + g * 4 + rr;
                const float bsc = (rr == 2) ? (-2.f * L2E) : (-L2E);
                bs[i][rr] = (row < 4 * HID)
                    ? (b_ih1[rr * HID + (row >> 2)] + b_hh1[rr * HID + (row >> 2)]) * bsc
                    : 0.f;
            }
            cs[i] = 0.f;
        }
        for (int s = 0; s < T_STEPS; ++s) {
            if (s >= 1) spin_ge(&FL[16], (unsigned)s);     // partner done s-1
            spin_ge(&FL[0], (unsigned)(s + 1));            // h0(s) published
            const unsigned short* sp = &SLOT[s & 3][0];
            const unsigned short* hp = &H1B[(s + 1) & 1][0];
            const short8 f0 = *(const short8*)&sp[g * 128 + m * 8];
            const short8 f1 = *(const short8*)&sp[(4 + g) * 128 + m * 8];
            const short8 f2 = *(const short8*)&hp[g * 128 + m * 8];
            const short8 f3 = *(const short8*)&hp[(4 + g) * 128 + m * 8];
            unsigned short* dp = &H1B[s & 1][0];
            #pragma unroll
            for (int i = 0; i < 7; ++i) {
                float4v accA = {bs[i][0], bs[i][1], bs[i][2], bs[i][3]};
                float4v accB = {0.f, 0.f, 0.f, 0.f};
                accA = MFMA_(wk1[i][0], f0, accA);
                accB = MFMA_(wk2[i][0], f2, accB);
                accA = MFMA_(wk1[i][1], f1, accA);
                accB = MFMA_(wk2[i][1], f3, accB);
                const float h1 = cell_(accA[0] + accB[0], accA[1] + accB[1],
                                       accA[2] + accB[2], accA[3] + accB[3], cs[i]);
                const int u = i * 4 + g;                   // <= 27, valid
                dp[(u >> 3) * 128 + m * 8 + (u & 7)] = (unsigned short)f2bf(h1);
            }
            post_(&FL[8], (unsigned)(s + 1), lead);
        }
    } else {
        // ============ wave B2: layer1 tiles 7..12 + FC + out ============
        short8 wk1[6][2], wk2[6][2];
        float  bs[6][4], cs[6];
        #pragma unroll
        for (int i = 0; i < 6; ++i) {
            const int T = 7 + i;
            const int r = T * 16 + m;
            const bool rv = (r < 4 * HID);
            const int orig = (r & 3) * HID + (r >> 2);
            const float rsc = ((r & 3) == 2) ? (-2.f * L2E) : (-L2E);
            const bool fcrow = (T == 12) && (m == 8);       // spare row 200
            #pragma unroll
            for (int q = 0; q < 2; ++q) {
                short8 a{}, b{};
                #pragma unroll
                for (int j = 0; j < 8; ++j) {
                    const int k = q * 32 + kb8 + j;
                    float v1 = 0.f, v2 = 0.f;
                    if (rv && k < HID) {
                        v1 = w_ih1[orig * HID + k] * rsc;
                        v2 = w_hh1[orig * HID + k] * rsc;
                    }
                    if (fcrow) v2 = (k < HID) ? fc_w[k] : 0.f;  // unscaled FC row
                    a[j] = (short)f2bf(v1);
                    b[j] = (short)f2bf(v2);
                }
                wk1[i][q] = a; wk2[i][q] = b;
            }
            #pragma unroll
            for (int rr = 0; rr < 4; ++rr) {
                const int row = T * 16 + g * 4 + rr;
                const float bsc = (rr == 2) ? (-2.f * L2E) : (-L2E);
                bs[i][rr] = (row < 4 * HID)
                    ? (b_ih1[rr * HID + (row >> 2)] + b_hh1[rr * HID + (row >> 2)]) * bsc
                    : 0.f;
                if (row == 4 * HID) bs[i][rr] = fc_b[0];    // FC bias (row 200)
            }
            cs[i] = 0.f;
        }
        for (int s = 0; s < T_STEPS; ++s) {
            if (s >= 1) spin_ge(&FL[8], (unsigned)s);      // partner done s-1
            spin_ge(&FL[0], (unsigned)(s + 1));            // h0(s) published
            const unsigned short* sp = &SLOT[s & 3][0];
            const unsigned short* hp = &H1B[(s + 1) & 1][0];
            const short8 f0 = *(const short8*)&sp[g * 128 + m * 8];
            const short8 f1 = *(const short8*)&sp[(4 + g) * 128 + m * 8];
            const short8 f2 = *(const short8*)&hp[g * 128 + m * 8];
            const short8 f3 = *(const short8*)&hp[(4 + g) * 128 + m * 8];
            unsigned short* dp = &H1B[s & 1][0];
            #pragma unroll
            for (int i = 0; i < 6; ++i) {
                float4v accA = {bs[i][0], bs[i][1], bs[i][2], bs[i][3]};
                float4v accB = {0.f, 0.f, 0.f, 0.f};
                accA = MFMA_(wk1[i][0], f0, accA);
                accB = MFMA_(wk2[i][0], f2, accB);
                accA = MFMA_(wk1[i][1], f1, accA);
                accB = MFMA_(wk2[i][1], f3, accB);
                const float a0 = accA[0] + accB[0];
                // FC output = spare row 200: fc_b + fc_w . h1(s-1) -> out[s-1]
                if (i == 5 && g == 2 && s >= 1)
                    out[(size_t)(s - 1) * BATCH + b0 + m] = a0;
                const float h1 = cell_(a0, accA[1] + accB[1],
                                       accA[2] + accB[2], accA[3] + accB[3], cs[i]);
                const int u = (7 + i) * 4 + g;
                if (i < 5) {
                    dp[(u >> 3) * 128 + m * 8 + (u & 7)] = (unsigned short)f2bf(h1);
                } else if (g < 2) {                         // tile 12: units 48,49
                    dp[(u >> 3) * 128 + m * 8 + (u & 7)] = (unsigned short)f2bf(h1);
                }
            }
            post_(&FL[16], (unsigned)(s + 1), lead);
        }
        // final FC on h1(364): out[364]
        spin_ge(&FL[8], (unsigned)T_STEPS);                // B1's last writes done
        const unsigned short* hp = &H1B[0][0];             // h1(364) parity buf
        const short8 f2 = *(const short8*)&hp[g * 128 + m * 8];
        const short8 f3 = *(const short8*)&hp[(4 + g) * 128 + m * 8];
        float4v acc = {bs[5][0], bs[5][1], bs[5][2], bs[5][3]};
        acc = MFMA_(wk2[5][0], f2, acc);
        acc = MFMA_(wk2[5][1], f3, acc);
        if (g == 2)
            out[(size_t)(T_STEPS - 1) * BATCH + b0 + m] = acc[0];
    }
}

extern "C" void kernel_launch(void* const* d_in, const int* in_sizes, int n_in,
                              void* d_out, int out_size, void* d_ws, size_t ws_size,
                              hipStream_t stream) {
    (void)d_ws; (void)ws_size; (void)in_sizes; (void)n_in; (void)out_size;
    const float* x     = (const float*)d_in[0];
    const float* w_ih0 = (const float*)d_in[1];
    const float* w_hh0 = (const float*)d_in[2];
    const float* b_ih0 = (const float*)d_in[3];
    const float* b_hh0 = (const float*)d_in[4];
    const float* w_ih1 = (const float*)d_in[5];
    const float* w_hh1 = (const float*)d_in[6];
    const float* b_ih1 = (const float*)d_in[7];
    const float* b_hh1 = (const float*)d_in[8];
    const float* fc_w  = (const float*)d_in[9];
    const float* fc_b  = (const float*)d_in[10];
    float* out = (float*)d_out;

    lstm_pc<<<dim3(NBLK), dim3(NT), 0, stream>>>(
        x, w_ih0, w_hh0, b_ih0, b_hh0,
        w_ih1, w_hh1, b_ih1, b_hh1, fc_w, fc_b, out);
}

// Round 15
// 333.167 us; speedup vs baseline: 1.8732x; 1.8732x over previous
//
#include <hip/hip_runtime.h>

#define T_STEPS 365
#define BATCH   2048
#define INP     9
#define HID     50
#define MB      16          // batch per block (MFMA col dim)
#define NBLK    (BATCH/MB)  // 128
#define NT      896         // 14 waves: 0-12 merged L0+L1 tiles, 13 util
#define NWC     13          // compute waves (13 tiles of 16 gate rows)
#define L2E     1.4426950408889634f

typedef __attribute__((ext_vector_type(8))) short short8;
typedef __attribute__((ext_vector_type(4))) float float4v;

__device__ __forceinline__ unsigned f2bf(float v) {
    unsigned u = __builtin_bit_cast(unsigned, v);
    return (u + 0x7FFFu + ((u >> 16) & 1u)) >> 16;
}

// lgkm-only phase barrier: LDS drains, global loads stay in flight.
#define PHASE_BARRIER() do {                                  \
    asm volatile("s_waitcnt lgkmcnt(0)" ::: "memory");        \
    __builtin_amdgcn_s_barrier();                             \
    __builtin_amdgcn_sched_barrier(0);                        \
} while (0)

// HX[p]: [16 batch rows][128 bf16 cols]: 0-49 h0 | 50-58 x | 59-63 zero | 64-113 h1 | 114-127 zero
// XOR swizzle keeps b128 fragment reads 2-way max (free per m136).
__device__ __forceinline__ int hx_off(int m, int k) {   // ushort units
    return (m * 128 + k) ^ ((m & 7) << 3);
}

// Merged-role LSTM: wave T computes BOTH layer0-tile T (step ph) and
// layer1-tile T (step ph-1) each phase — two independent dependency chains
// per wave, interleaved by the compiler. One lgkm-only barrier per phase.
// Measured best of 15 structural variants: 334 µs (r9).
__global__ __launch_bounds__(NT, 3)
void lstm_merged(const float* __restrict__ x,
                 const float* __restrict__ w_ih0, const float* __restrict__ w_hh0,
                 const float* __restrict__ b_ih0, const float* __restrict__ b_hh0,
                 const float* __restrict__ w_ih1, const float* __restrict__ w_hh1,
                 const float* __restrict__ b_ih1, const float* __restrict__ b_hh1,
                 const float* __restrict__ fc_w, const float* __restrict__ fc_b,
                 float* __restrict__ out)
{
    __shared__ __align__(16) unsigned short HX[2][MB * 128];
    __shared__ float FCP[2][NWC][MB];

    const int tid  = threadIdx.x;
    const int w    = tid >> 6;
    const int lid  = tid & 63;
    const int mcol = lid & 15;
    const int kgrp = lid >> 4;
    const int kb8  = kgrp * 8;
    const int b0   = blockIdx.x * MB;
    const bool cw  = (w < NWC);
    const float fcb = fc_b[0];

    // ---- per-wave tile identity (gate-interleaved rows: r = 4*unit + gate
    //      -> original row = gate*50 + unit) ----
    const int T = cw ? w : 0;
    const int r = T * 16 + mcol;
    const bool rv = cw && (r < 4 * HID);
    const int u_r = r >> 2, g_r = r & 3;
    const int orig = g_r * HID + u_r;
    const float rsc = (g_r == 2) ? (-2.f * L2E) : (-L2E);   // exp2 prescale
    const int u = T * 4 + kgrp;              // unit this lane's D-regs cover

    // wk0: L0 [w_hh0 on h0(50) | w_ih0 on x(9) | 0]  (K=64, 2 halves)
    // wk1: L1 w_ih1 on h0(50)   (cols 50-63 zero -> x contamination killed)
    // wk2: L1 w_hh1 on h1(50)
    short8 wk0[2], wk1[2], wk2[2];
    #pragma unroll
    for (int q = 0; q < 2; ++q) {
        short8 a{}, b{}, c{};
        #pragma unroll
        for (int j = 0; j < 8; ++j) {
            const int k = q * 32 + kb8 + j;
            float v0 = 0.f, v1 = 0.f, v2 = 0.f;
            if (rv) {
                if (k < HID) {
                    v0 = w_hh0[orig * HID + k];
                    v1 = w_ih1[orig * HID + k];
                    v2 = w_hh1[orig * HID + k];
                } else if (k < HID + INP) {
                    v0 = w_ih0[orig * INP + (k - HID)];
                }
            }
            a[j] = (short)f2bf(v0 * rsc);
            b[j] = (short)f2bf(v1 * rsc);
            c[j] = (short)f2bf(v2 * rsc);
        }
        wk0[q] = a; wk1[q] = b; wk2[q] = c;
    }
    float bs0[4], bs1[4];
    #pragma unroll
    for (int rr = 0; rr < 4; ++rr) {
        const int row = T * 16 + kgrp * 4 + rr;   // = 4*u + rr
        const bool bv = cw && (row < 4 * HID);
        const float bsc = (rr == 2) ? (-2.f * L2E) : (-L2E);
        bs0[rr] = bv ? (b_ih0[rr * HID + u] + b_hh0[rr * HID + u]) * bsc : 0.f;
        bs1[rr] = bv ? (b_ih1[rr * HID + u] + b_hh1[rr * HID + u]) * bsc : 0.f;
    }
    const float fcwv = (cw && u < HID) ? fc_w[u] : 0.f;
    float cst0 = 0.f, cst1 = 0.f;

    // ---- util wave (w == NWC): lanes 0-47 load x (3 values each),
    //      lanes 48-63 write out ----
    const bool xact = (!cw) && (lid < 48);
    const bool oact = (!cw) && (lid >= 48);
    const int om = lid - 48;
    float xr[3] = {0.f, 0.f, 0.f};

    // ---- LDS init ----
    for (int i = tid; i < 2 * MB * 128; i += NT) (&HX[0][0])[i] = 0;
    for (int i = tid; i < 2 * NWC * MB; i += NT) (&FCP[0][0][0])[i] = 0.f;
    __syncthreads();
    if (xact) {
        #pragma unroll
        for (int q = 0; q < 3; ++q) {
            const int xi = lid * 3 + q;
            if (xi < MB * INP) {
                const int m = xi / INP, j = xi - m * INP;
                // x(0) into buf1 (phase 0 reads cur = 1); xr <- x(1)
                HX[1][hx_off(m, HID + j)] =
                    (unsigned short)f2bf(x[(size_t)(b0 + m) * INP + j]);
                xr[q] = x[((size_t)BATCH + b0 + m) * INP + j];
            }
        }
    }
    __syncthreads();

    for (int ph = 0; ph <= T_STEPS + 1; ++ph) {
        const int cur = (ph + 1) & 1, nxt = ph & 1;

        if (cw) {
            // shared fragment reads: f0/f1 feed BOTH chains (h0(ph-1)+x(ph));
            // f2/f3 feed the L1 chain (h1(ph-2)).
            const short8 f0 = *(const short8*)&HX[cur][hx_off(mcol, kb8)];
            const short8 f1 = *(const short8*)&HX[cur][hx_off(mcol, 32 + kb8)];
            const short8 f2 = *(const short8*)&HX[cur][hx_off(mcol, 64 + kb8)];
            const short8 f3 = *(const short8*)&HX[cur][hx_off(mcol, 96 + kb8)];

            // ---- chain A: layer0 step ph ----
            if (ph < T_STEPS) {
                float4v acc = {bs0[0], bs0[1], bs0[2], bs0[3]};
                acc = __builtin_amdgcn_mfma_f32_16x16x32_bf16(wk0[0], f0, acc, 0, 0, 0);
                acc = __builtin_amdgcn_mfma_f32_16x16x32_bf16(wk0[1], f1, acc, 0, 0, 0);
                const float gi = __builtin_amdgcn_rcpf(1.f + __builtin_amdgcn_exp2f(acc[0]));
                const float gf = __builtin_amdgcn_rcpf(1.f + __builtin_amdgcn_exp2f(acc[1]));
                const float g2 = __builtin_amdgcn_rcpf(1.f + __builtin_amdgcn_exp2f(acc[2]));
                const float go = __builtin_amdgcn_rcpf(1.f + __builtin_amdgcn_exp2f(acc[3]));
                const float gg = __builtin_fmaf(2.f, g2, -1.f);
                cst0 = gf * cst0 + gi * gg;
                const float Ec = __builtin_amdgcn_exp2f(cst0 * (-2.f * L2E));
                const float tc = __builtin_fmaf(2.f, __builtin_amdgcn_rcpf(1.f + Ec), -1.f);
                const float h0v = go * tc;
                if (u < HID) HX[nxt][hx_off(mcol, u)] = (unsigned short)f2bf(h0v);
            }

            // ---- chain B: layer1 step ph-1 (+ FC partial) ----
            if (ph >= 1 && ph <= T_STEPS) {
                float4v accA = {bs1[0], bs1[1], bs1[2], bs1[3]};
                float4v accB = {0.f, 0.f, 0.f, 0.f};
                accA = __builtin_amdgcn_mfma_f32_16x16x32_bf16(wk1[0], f0, accA, 0, 0, 0);
                accB = __builtin_amdgcn_mfma_f32_16x16x32_bf16(wk2[0], f2, accB, 0, 0, 0);
                accA = __builtin_amdgcn_mfma_f32_16x16x32_bf16(wk1[1], f1, accA, 0, 0, 0);
                accB = __builtin_amdgcn_mfma_f32_16x16x32_bf16(wk2[1], f3, accB, 0, 0, 0);
                const float gi = __builtin_amdgcn_rcpf(1.f + __builtin_amdgcn_exp2f(accA[0] + accB[0]));
                const float gf = __builtin_amdgcn_rcpf(1.f + __builtin_amdgcn_exp2f(accA[1] + accB[1]));
                const float g2 = __builtin_amdgcn_rcpf(1.f + __builtin_amdgcn_exp2f(accA[2] + accB[2]));
                const float go = __builtin_amdgcn_rcpf(1.f + __builtin_amdgcn_exp2f(accA[3] + accB[3]));
                const float gg = __builtin_fmaf(2.f, g2, -1.f);
                cst1 = gf * cst1 + gi * gg;
                const float Ec = __builtin_amdgcn_exp2f(cst1 * (-2.f * L2E));
                const float tc = __builtin_fmaf(2.f, __builtin_amdgcn_rcpf(1.f + Ec), -1.f);
                const float h1v = go * tc;
                if (u < HID) HX[nxt][hx_off(mcol, 64 + u)] = (unsigned short)f2bf(h1v);
                float fcp = fcwv * h1v;
                fcp += __shfl_xor(fcp, 16);
                fcp += __shfl_xor(fcp, 32);
                if (lid < MB) FCP[ph & 1][w][lid] = fcp;
            }
        } else if (xact) {
            // ---- x staging: write x(ph+1) (loaded 2 phases ago), load x(ph+2) ----
            #pragma unroll
            for (int q = 0; q < 3; ++q) {
                const int xi = lid * 3 + q;
                if (xi < MB * INP) {
                    const int m = xi / INP, j = xi - m * INP;
                    float xn = 0.f;
                    if (ph + 2 < T_STEPS)
                        xn = x[((size_t)(ph + 2) * BATCH + b0 + m) * INP + j];
                    if (ph + 1 < T_STEPS)
                        HX[nxt][hx_off(m, HID + j)] = (unsigned short)f2bf(xr[q]);
                    xr[q] = xn;
                }
            }
        } else if (oact && ph >= 2) {
            // ---- out writer: out[ph-2] from FCP written at phase ph-1 ----
            const int rp = (ph - 1) & 1;
            float s = fcb;
            #pragma unroll
            for (int vv = 0; vv < NWC; ++vv) s += FCP[rp][vv][om];
            out[(size_t)(ph - 2) * BATCH + b0 + om] = s;
        }
        PHASE_BARRIER();
    }
}

extern "C" void kernel_launch(void* const* d_in, const int* in_sizes, int n_in,
                              void* d_out, int out_size, void* d_ws, size_t ws_size,
                              hipStream_t stream) {
    const float* x     = (const float*)d_in[0];
    const float* w_ih0 = (const float*)d_in[1];
    const float* w_hh0 = (const float*)d_in[2];
    const float* b_ih0 = (const float*)d_in[3];
    const float* b_hh0 = (const float*)d_in[4];
    const float* w_ih1 = (const float*)d_in[5];
    const float* w_hh1 = (const float*)d_in[6];
    const float* b_ih1 = (const float*)d_in[7];
    const float* b_hh1 = (const float*)d_in[8];
    const float* fc_w  = (const float*)d_in[9];
    const float* fc_b  = (const float*)d_in[10];
    float* out = (float*)d_out;

    lstm_merged<<<dim3(NBLK), dim3(NT), 0, stream>>>(
        x, w_ih0, w_hh0, b_ih0, b_hh0,
        w_ih1, w_hh1, b_ih1, b_hh1, fc_w, fc_b, out);
}